// Round 6
// baseline (232.506 us; speedup 1.0000x reference)
//
#include <hip/hip_runtime.h>

#define IMG_W 512
#define IMG_H 512
#define NPLANES 48         // 16 * 3
#define NPIX 12582912.0    // 16*3*512*512
#define CST 44             // column stride (words): 42 ext rows padded to 44
#define FSZ (32 * CST)     // words per field = 1408
#define NBLOCKS (16*16*48) // 12288

// Transposed h-layout: element (field f, tile col c, ext row r) at
//   f*FSZ + c*CST + r.
// READS (vertical, ds_read_b128): per 16-lane quarter, base banks 12c mod 32
// cover all eight 4-bank groups twice -> 2 words/bank = conflict-free.
// WRITES (horizontal, scalar): wave lane set remapped to (4 col-groups x 16
// rows) so bank = 16(m&1) + 12o + r with r spanning 16 -> exactly 2
// lanes/bank = free (vs R3's (8x8) assignment which was 4-way).

__global__ __launch_bounds__(256) void ssim_fused_kernel(
    const float* __restrict__ pred,
    const float* __restrict__ label,
    float* __restrict__ partial)
{
    __shared__ float hT[5 * FSZ];   // 28160 B -> 5 blocks/CU

    // Normalized 11-tap Gaussian, sigma=1.5 (literals validated in R5).
    const float w[11] = { 0.00102838f, 0.00759876f, 0.03600077f, 0.10936069f,
                          0.21300554f, 0.26601173f, 0.21300554f, 0.10936069f,
                          0.03600077f, 0.00759876f, 0.00102838f };

    const int tid = threadIdx.x;
    const int ox = blockIdx.x * 32;
    const int oy = blockIdx.y * 32;
    const int plane = blockIdx.z;
    const float* __restrict__ xp = pred  + (size_t)plane * (IMG_W * IMG_H);
    const float* __restrict__ yp = label + (size_t)plane * (IMG_W * IMG_H);

    // ---- Horizontal pass: 42 ext rows x 8 groups of 4 cols = 336 tasks ----
    // Lane decomposition: wave covers (4 col-groups) x (16 rows).
    const bool xInterior = (blockIdx.x != 0) && (blockIdx.x != (IMG_W / 32 - 1));
    for (int i = tid; i < 384; i += 256) {
        int g = ((i >> 6) & 1) * 4 + (i & 3);            // col group 0..7
        int r = ((i >> 7) << 4) + ((i >> 2) & 15);       // ext row 0..47
        if (r < 42) {
            int gy = oy - 5 + r;
            int c0 = ox + g * 4;      // first output col (global)

            float bx_[24], by_[24];
            bool rowok = ((unsigned)gy < (unsigned)IMG_H);
            if (!rowok) {
                #pragma unroll
                for (int j = 0; j < 24; ++j) { bx_[j] = 0.f; by_[j] = 0.f; }
            } else if (xInterior) {
                const float4* px4 = reinterpret_cast<const float4*>(xp + gy * IMG_W + (c0 - 8));
                const float4* py4 = reinterpret_cast<const float4*>(yp + gy * IMG_W + (c0 - 8));
                #pragma unroll
                for (int j = 0; j < 6; ++j) {
                    float4 a = px4[j];
                    float4 b = py4[j];
                    bx_[4*j+0] = a.x; bx_[4*j+1] = a.y; bx_[4*j+2] = a.z; bx_[4*j+3] = a.w;
                    by_[4*j+0] = b.x; by_[4*j+1] = b.y; by_[4*j+2] = b.z; by_[4*j+3] = b.w;
                }
            } else {
                #pragma unroll
                for (int j = 0; j < 24; ++j) {
                    int col = c0 - 8 + j;
                    bool ok = ((unsigned)col < (unsigned)IMG_W);
                    bx_[j] = ok ? xp[gy * IMG_W + col] : 0.f;
                    by_[j] = ok ? yp[gy * IMG_W + col] : 0.f;
                }
            }

            float a0[4] = {0,0,0,0}, a1[4] = {0,0,0,0}, a2[4] = {0,0,0,0},
                  a3[4] = {0,0,0,0}, a4[4] = {0,0,0,0};
            // output o taps window cols j = o+3 .. o+13
            #pragma unroll
            for (int j = 3; j <= 16; ++j) {
                float xv = bx_[j], yv = by_[j];
                float xx = xv * xv, yy = yv * yv, xy = xv * yv;
                #pragma unroll
                for (int o = 0; o < 4; ++o) {
                    int k = j - 3 - o;
                    if (k >= 0 && k <= 10) {
                        float wk = w[k];
                        a0[o] += wk * xv;
                        a1[o] += wk * yv;
                        a2[o] += wk * xx;
                        a3[o] += wk * yy;
                        a4[o] += wk * xy;
                    }
                }
            }

            // Scalar writes: one base + 20 immediate offsets; 2-way banks.
            int wb = g * (4 * CST) + r;
            #pragma unroll
            for (int o = 0; o < 4; ++o) {
                hT[wb + o*CST + 0*FSZ] = a0[o];
                hT[wb + o*CST + 1*FSZ] = a1[o];
                hT[wb + o*CST + 2*FSZ] = a2[o];
                hT[wb + o*CST + 3*FSZ] = a3[o];
                hT[wb + o*CST + 4*FSZ] = a4[o];
            }
        }
    }
    __syncthreads();

    // ---- Vertical pass: 32 cols x 8 row-groups of 4 = 256 tasks ----
    float lsum = 0.f;
    {
        int c  = tid & 31;
        int rg = tid >> 5;        // output rows 4*rg .. 4*rg+3
        int d  = c * CST + 4 * rg;

        float m[5][4];
        #pragma unroll
        for (int f = 0; f < 5; ++f) {
            const float4* p = reinterpret_cast<const float4*>(&hT[f*FSZ + d]);
            float4 v0 = p[0], v1 = p[1], v2 = p[2], v3 = p[3];
            float vv[16] = { v0.x, v0.y, v0.z, v0.w,
                             v1.x, v1.y, v1.z, v1.w,
                             v2.x, v2.y, v2.z, v2.w,
                             v3.x, v3.y, v3.z, v3.w };
            #pragma unroll
            for (int o = 0; o < 4; ++o) {
                float s = 0.f;
                #pragma unroll
                for (int k = 0; k < 11; ++k) s += w[k] * vv[o + k];
                m[f][o] = s;
            }
        }

        #pragma unroll
        for (int o = 0; o < 4; ++o) {
            float mu1 = m[0][o], mu2 = m[1][o];
            float mu1s = mu1 * mu1, mu2s = mu2 * mu2, mu12 = mu1 * mu2;
            float s1  = m[2][o] - mu1s;
            float s2  = m[3][o] - mu2s;
            float s12 = m[4][o] - mu12;
            const float C1 = 1e-4f, C2 = 9e-4f;
            float num = (2.f * mu12 + C1) * (2.f * s12 + C2);
            float den = (mu1s + mu2s + C1) * (s1 + s2 + C2);
            lsum += num * __builtin_amdgcn_rcpf(den);
        }
    }

    // ---- Block reduction -> one float partial per block ----
    #pragma unroll
    for (int off = 32; off > 0; off >>= 1)
        lsum += __shfl_down(lsum, off, 64);

    __shared__ float wsum[4];
    if ((tid & 63) == 0) wsum[tid >> 6] = lsum;
    __syncthreads();
    if (tid == 0) {
        int bid = (blockIdx.z * gridDim.y + blockIdx.y) * gridDim.x + blockIdx.x;
        partial[bid] = wsum[0] + wsum[1] + wsum[2] + wsum[3];
    }
}

__global__ __launch_bounds__(1024) void ssim_finalize_kernel(
    const float* __restrict__ partial, float* __restrict__ out)
{
    double s = 0.0;
    for (int i = threadIdx.x; i < NBLOCKS; i += 1024) s += (double)partial[i];
    #pragma unroll
    for (int off = 32; off > 0; off >>= 1) s += __shfl_down(s, off, 64);
    __shared__ double ws[16];
    if ((threadIdx.x & 63) == 0) ws[threadIdx.x >> 6] = s;
    __syncthreads();
    if (threadIdx.x == 0) {
        double t = 0.0;
        #pragma unroll
        for (int k = 0; k < 16; ++k) t += ws[k];
        out[0] = 1.0f - (float)(t * (1.0 / NPIX));
    }
}

extern "C" void kernel_launch(void* const* d_in, const int* in_sizes, int n_in,
                              void* d_out, int out_size, void* d_ws, size_t ws_size,
                              hipStream_t stream) {
    const float* pred  = (const float*)d_in[0];
    const float* label = (const float*)d_in[1];
    float* out = (float*)d_out;
    float* partial = (float*)d_ws;   // NBLOCKS floats, fully overwritten every call

    dim3 grid(IMG_W / 32, IMG_H / 32, NPLANES);
    ssim_fused_kernel<<<grid, 256, 0, stream>>>(pred, label, partial);
    ssim_finalize_kernel<<<1, 1024, 0, stream>>>(partial, out);
}

// Round 8
// 180.689 us; speedup vs baseline: 1.2868x; 1.2868x over previous
//
#include <hip/hip_runtime.h>

#define IMG_W 512
#define IMG_H 512
#define NPLANES 48         // 16 * 3
#define NPIX 12582912.0    // 16*3*512*512
#define CST 44             // column stride (words): 42 ext rows padded to 44
#define FSZ (32 * CST)     // words per field = 1408
#define NBLOCKS (16*16*48) // 12288

// R3 configuration (measured best: 103.7 us): transposed h-layout
//   addr(f, c, r) = f*FSZ + c*CST + r
// READS (vertical b128): per 16-lane quarter, base banks 12c mod 32 cover all
// eight 4-bank groups twice -> conflict-free (2 words/bank minimum).
// WRITES (horizontal scalar): 4-way structural (16g mod 32 in {0,16}) — costs
// only ~7 us (m136 4-way=1.58x on ~105 write-instr/block); accepted.
// Weights: expf-computed into VGPRs (literal-weight FMAs are 2-dword instrs;
// R5/R6 literal builds showed VALUBusy 66->43% collapse).

__global__ __launch_bounds__(256) void ssim_fused_kernel(
    const float* __restrict__ pred,
    const float* __restrict__ label,
    float* __restrict__ partial)
{
    __shared__ float hT[5 * FSZ];   // 28160 B -> 5 blocks/CU

    const int tid = threadIdx.x;
    const int ox = blockIdx.x * 32;
    const int oy = blockIdx.y * 32;
    const int plane = blockIdx.z;
    const float* __restrict__ xp = pred  + (size_t)plane * (IMG_W * IMG_H);
    const float* __restrict__ yp = label + (size_t)plane * (IMG_W * IMG_H);

    // Gaussian weights (sigma=1.5, K=11), normalized — registers, not literals.
    float w[11];
    {
        float s = 0.f;
        #pragma unroll
        for (int i = 0; i < 11; ++i) {
            float d = (float)(i - 5);
            w[i] = expf(-d * d / 4.5f);
            s += w[i];
        }
        float inv = 1.0f / s;
        #pragma unroll
        for (int i = 0; i < 11; ++i) w[i] *= inv;
    }

    // ---- Horizontal pass: 42 ext rows x 8 groups of 4 cols = 336 tasks ----
    // R3 lane map: r = i>>3 (8 rows/wave-instr), g = i&7.
    const bool xInterior = (blockIdx.x != 0) && (blockIdx.x != (IMG_W / 32 - 1));
    for (int i = tid; i < 336; i += 256) {
        int r  = i >> 3;          // ext row 0..41
        int g  = i & 7;           // col group 0..7
        int gy = oy - 5 + r;
        int c0 = ox + g * 4;      // first output col of this group (global)

        float bx_[24], by_[24];
        bool rowok = ((unsigned)gy < (unsigned)IMG_H);
        if (!rowok) {
            #pragma unroll
            for (int j = 0; j < 24; ++j) { bx_[j] = 0.f; by_[j] = 0.f; }
        } else if (xInterior) {
            const float4* px4 = reinterpret_cast<const float4*>(xp + gy * IMG_W + (c0 - 8));
            const float4* py4 = reinterpret_cast<const float4*>(yp + gy * IMG_W + (c0 - 8));
            #pragma unroll
            for (int j = 0; j < 6; ++j) {
                float4 a = px4[j];
                float4 b = py4[j];
                bx_[4*j+0] = a.x; bx_[4*j+1] = a.y; bx_[4*j+2] = a.z; bx_[4*j+3] = a.w;
                by_[4*j+0] = b.x; by_[4*j+1] = b.y; by_[4*j+2] = b.z; by_[4*j+3] = b.w;
            }
        } else {
            #pragma unroll
            for (int j = 0; j < 24; ++j) {
                int col = c0 - 8 + j;
                bool ok = ((unsigned)col < (unsigned)IMG_W);
                bx_[j] = ok ? xp[gy * IMG_W + col] : 0.f;
                by_[j] = ok ? yp[gy * IMG_W + col] : 0.f;
            }
        }

        float a0[4] = {0,0,0,0}, a1[4] = {0,0,0,0}, a2[4] = {0,0,0,0},
              a3[4] = {0,0,0,0}, a4[4] = {0,0,0,0};
        // output o taps window cols j = o+3 .. o+13
        #pragma unroll
        for (int j = 3; j <= 16; ++j) {
            float xv = bx_[j], yv = by_[j];
            float xx = xv * xv, yy = yv * yv, xy = xv * yv;
            #pragma unroll
            for (int o = 0; o < 4; ++o) {
                int k = j - 3 - o;
                if (k >= 0 && k <= 10) {
                    float wk = w[k];
                    a0[o] += wk * xv;
                    a1[o] += wk * yv;
                    a2[o] += wk * xx;
                    a3[o] += wk * yy;
                    a4[o] += wk * xy;
                }
            }
        }

        // Scalar writes: one base + 20 immediate offsets (4-way banks, accepted).
        int wb = g * (4 * CST) + r;
        #pragma unroll
        for (int o = 0; o < 4; ++o) {
            hT[wb + o*CST + 0*FSZ] = a0[o];
            hT[wb + o*CST + 1*FSZ] = a1[o];
            hT[wb + o*CST + 2*FSZ] = a2[o];
            hT[wb + o*CST + 3*FSZ] = a3[o];
            hT[wb + o*CST + 4*FSZ] = a4[o];
        }
    }
    __syncthreads();

    // ---- Vertical pass: 32 cols x 8 row-groups of 4 = 256 tasks ----
    float lsum = 0.f;
    {
        int c  = tid & 31;
        int rg = tid >> 5;        // output rows 4*rg .. 4*rg+3
        int d  = c * CST + 4 * rg;

        float m[5][4];
        #pragma unroll
        for (int f = 0; f < 5; ++f) {
            const float4* p = reinterpret_cast<const float4*>(&hT[f*FSZ + d]);
            float4 v0 = p[0], v1 = p[1], v2 = p[2], v3 = p[3];
            float vv[16] = { v0.x, v0.y, v0.z, v0.w,
                             v1.x, v1.y, v1.z, v1.w,
                             v2.x, v2.y, v2.z, v2.w,
                             v3.x, v3.y, v3.z, v3.w };
            #pragma unroll
            for (int o = 0; o < 4; ++o) {
                float s = 0.f;
                #pragma unroll
                for (int k = 0; k < 11; ++k) s += w[k] * vv[o + k];
                m[f][o] = s;
            }
        }

        #pragma unroll
        for (int o = 0; o < 4; ++o) {
            float mu1 = m[0][o], mu2 = m[1][o];
            float mu1s = mu1 * mu1, mu2s = mu2 * mu2, mu12 = mu1 * mu2;
            float s1  = m[2][o] - mu1s;
            float s2  = m[3][o] - mu2s;
            float s12 = m[4][o] - mu12;
            const float C1 = 1e-4f, C2 = 9e-4f;
            float num = (2.f * mu12 + C1) * (2.f * s12 + C2);
            float den = (mu1s + mu2s + C1) * (s1 + s2 + C2);
            lsum += num * __builtin_amdgcn_rcpf(den);
        }
    }

    // ---- Block reduction -> one float partial per block ----
    #pragma unroll
    for (int off = 32; off > 0; off >>= 1)
        lsum += __shfl_down(lsum, off, 64);

    __shared__ float wsum[4];
    if ((tid & 63) == 0) wsum[tid >> 6] = lsum;
    __syncthreads();
    if (tid == 0) {
        int bid = (blockIdx.z * gridDim.y + blockIdx.y) * gridDim.x + blockIdx.x;
        partial[bid] = wsum[0] + wsum[1] + wsum[2] + wsum[3];
    }
}

__global__ __launch_bounds__(1024) void ssim_finalize_kernel(
    const float* __restrict__ partial, float* __restrict__ out)
{
    double s = 0.0;
    for (int i = threadIdx.x; i < NBLOCKS; i += 1024) s += (double)partial[i];
    #pragma unroll
    for (int off = 32; off > 0; off >>= 1) s += __shfl_down(s, off, 64);
    __shared__ double ws[16];
    if ((threadIdx.x & 63) == 0) ws[threadIdx.x >> 6] = s;
    __syncthreads();
    if (threadIdx.x == 0) {
        double t = 0.0;
        #pragma unroll
        for (int k = 0; k < 16; ++k) t += ws[k];
        out[0] = 1.0f - (float)(t * (1.0 / NPIX));
    }
}

extern "C" void kernel_launch(void* const* d_in, const int* in_sizes, int n_in,
                              void* d_out, int out_size, void* d_ws, size_t ws_size,
                              hipStream_t stream) {
    const float* pred  = (const float*)d_in[0];
    const float* label = (const float*)d_in[1];
    float* out = (float*)d_out;
    float* partial = (float*)d_ws;   // NBLOCKS floats, fully overwritten every call

    dim3 grid(IMG_W / 32, IMG_H / 32, NPLANES);
    ssim_fused_kernel<<<grid, 256, 0, stream>>>(pred, label, partial);
    ssim_finalize_kernel<<<1, 1024, 0, stream>>>(partial, out);
}